// Round 16
// baseline (8074.452 us; speedup 1.0000x reference)
//
#include <hip/hip_runtime.h>
#include <math.h>

#define NHEADS 16
#define HD 64
#define MMEM 16384
#define NQ 1024   // B*S per head
#define SEQ 512
#define EPS 1e-8f
#define NPART 32
#define NT 16     // 32-mem tiles per partition (16384/32/32)
#define NGRP 64   // candidate groups per query: NPART * 2 halves
#define CMAX 4    // candidate slots per (query, group)
#define CHT 2     // tiles per staged chunk (8 KB)
#define NCHUNK 8  // chunks per partition (NT/CHT)

typedef short bf16x8 __attribute__((ext_vector_type(8)));
typedef float f32x16 __attribute__((ext_vector_type(16)));

typedef const __attribute__((address_space(1))) unsigned int* gas_u32p;
typedef __attribute__((address_space(3))) unsigned int* las_u32p;

__device__ inline unsigned short f2bf(float f) {
    unsigned int u = __builtin_bit_cast(unsigned int, f);
    unsigned int r = (u + 0x7FFFu + ((u >> 16) & 1u)) >> 16;  // RNE
    return (unsigned short)r;
}

#define SS(Q) (Q.x*Q.x + Q.y*Q.y + Q.z*Q.z + Q.w*Q.w)

// ---------------------------------------------------------------------------
// Kernel 1: fused knorm + kprep. Block = one (h,tile): 32 rows x 64 d,
// 4 ks-slices. Row 1/||k|| via one LDS round; writes knr AND normalized bf16
// keys in MFMA-A tile order:
// (((h*512+t)*4+ks)*64+lane)*8 elems = kmem[h][t*32+(lane&31)][ks*16+(lane>>5)*8+j]*rn.
// ---------------------------------------------------------------------------
__global__ __launch_bounds__(256)
void kprep_kernel(const float* __restrict__ kmem,
                  float* __restrict__ knr,
                  unsigned short* __restrict__ kbf) {
    __shared__ float ssl[256];
    const int tid = threadIdx.x;
    const int gid = blockIdx.x * 256 + tid;
    const int lane = gid & 63;
    const int ks   = (gid >> 6) & 3;
    const int t    = (gid >> 8) & 511;
    const int h    = gid >> 17;
    const int r    = lane & 31;
    const int hi   = lane >> 5;
    const int row  = t * 32 + r;
    const int d0   = ks * 16 + hi * 8;

    const float* src = kmem + (((size_t)h * MMEM + row) << 6) + d0;
    float4 v0 = *(const float4*)(src);
    float4 v1 = *(const float4*)(src + 4);
    ssl[tid] = SS(v0) + SS(v1);      // tid = ks*64 + hi*32 + r
    __syncthreads();
    float tot = ssl[r +   0] + ssl[r +  32] + ssl[r +  64] + ssl[r +  96]
              + ssl[r + 128] + ssl[r + 160] + ssl[r + 192] + ssl[r + 224];
    const float rn = 1.0f / fmaxf(sqrtf(tot), EPS);
    if (tid < 32) knr[h * MMEM + row] = rn;

    uint4 o;
    o.x = (unsigned)f2bf(v0.x * rn) | ((unsigned)f2bf(v0.y * rn) << 16);
    o.y = (unsigned)f2bf(v0.z * rn) | ((unsigned)f2bf(v0.w * rn) << 16);
    o.z = (unsigned)f2bf(v1.x * rn) | ((unsigned)f2bf(v1.y * rn) << 16);
    o.w = (unsigned)f2bf(v1.z * rn) | ((unsigned)f2bf(v1.w * rn) << 16);
    *(uint4*)(kbf + (size_t)gid * 8) = o;
}

// ---------------------------------------------------------------------------
// Shared scan helpers
// ---------------------------------------------------------------------------
__device__ inline float max16v(const f32x16& a) {
    float m0 = fmaxf(fmaxf(a[0],  a[1]),  a[2]);
    float m1 = fmaxf(fmaxf(a[3],  a[4]),  a[5]);
    float m2 = fmaxf(fmaxf(a[6],  a[7]),  a[8]);
    float m3 = fmaxf(fmaxf(a[9],  a[10]), a[11]);
    float m4 = fmaxf(fmaxf(a[12], a[13]), a[14]);
    float n0 = fmaxf(fmaxf(m0, m1), m2);
    float n1 = fmaxf(fmaxf(m3, m4), a[15]);
    return fmaxf(n0, n1);
}

__device__ inline void ins8(float (&tv)[8], float v) {
#pragma unroll
    for (int j = 0; j < 8; ++j) {
        float h_ = fmaxf(tv[j], v);
        float l_ = fminf(tv[j], v);
        tv[j] = h_;
        v = l_;
    }
}

__device__ inline void ins8u64(unsigned long long (&tv)[8], unsigned long long v) {
#pragma unroll
    for (int j = 0; j < 8; ++j) {
        unsigned long long h_ = tv[j] > v ? tv[j] : v;
        unsigned long long l_ = tv[j] > v ? v : tv[j];
        tv[j] = h_;
        v = l_;
    }
}

__device__ inline bf16x8 pack8f(float4 a, float4 b) {
    bf16x8 f;
    f[0] = (short)f2bf(a.x); f[1] = (short)f2bf(a.y);
    f[2] = (short)f2bf(a.z); f[3] = (short)f2bf(a.w);
    f[4] = (short)f2bf(b.x); f[5] = (short)f2bf(b.y);
    f[6] = (short)f2bf(b.z); f[7] = (short)f2bf(b.w);
    return f;
}

// two query-groups per tile, both accs seeded from loop-invariant zero C
#define MFMA8Z(ACCA, ACCB, A0, A1, A2, A3)                                    \
    f32x16 ACCA = __builtin_amdgcn_mfma_f32_32x32x16_bf16(A0, qA[0], z16, 0,0,0); \
    f32x16 ACCB = __builtin_amdgcn_mfma_f32_32x32x16_bf16(A0, qB[0], z16, 0,0,0); \
    ACCA = __builtin_amdgcn_mfma_f32_32x32x16_bf16(A1, qA[1], ACCA, 0, 0, 0); \
    ACCB = __builtin_amdgcn_mfma_f32_32x32x16_bf16(A1, qB[1], ACCB, 0, 0, 0); \
    ACCA = __builtin_amdgcn_mfma_f32_32x32x16_bf16(A2, qA[2], ACCA, 0, 0, 0); \
    ACCB = __builtin_amdgcn_mfma_f32_32x32x16_bf16(A2, qB[2], ACCB, 0, 0, 0); \
    ACCA = __builtin_amdgcn_mfma_f32_32x32x16_bf16(A3, qA[3], ACCA, 0, 0, 0); \
    ACCB = __builtin_amdgcn_mfma_f32_32x32x16_bf16(A3, qB[3], ACCB, 0, 0, 0);

// stage one chunk (CHT tiles = CHT*4096 B) into lds buffer via global_load_lds
#define STAGE(CH) do {                                                        \
        const unsigned char* _s = gsrc + (size_t)(CH) * (CHT * 4096);         \
        unsigned char* _d = &lds[(CH) & 1][0];                                \
        _Pragma("unroll")                                                     \
        for (int _j = 0; _j < CHT; ++_j)                                      \
            __builtin_amdgcn_global_load_lds(                                 \
                (gas_u32p)(const void*)(_s + _j * 4096 + tid * 16),           \
                (las_u32p)(void*)(_d + _j * 4096 + tid * 16), 16, 0, 0);      \
    } while (0)

// ---------------------------------------------------------------------------
// Kernel 2 (scanA): MFMA pass 1, multi-wave LDS tile sharing. NPART=32 +
// CHT=2 (16 KB LDS/block) + launch_bounds(256,6): grid 2048 blocks -> up to
// 6 resident blocks/CU (24 waves) for latency overlap.
// Block = 4 waves x 64 queries = 256 queries x one partition (512 mems).
// Selection = one running fmax per (query, half) -> pmax[q][p*2+hi].
// D-layout: col=lane&31 (query), row=(reg&3)+8*(reg>>2)+4*(lane>>5) (mem).
// ---------------------------------------------------------------------------
__global__ __launch_bounds__(256, 6)
void scanA_kernel(const float* __restrict__ query,
                  const unsigned short* __restrict__ kbf,
                  float* __restrict__ pmax) {
    __shared__ __align__(16) unsigned char lds[2][CHT * 4096];
    const int tid  = threadIdx.x;
    const int lane = tid & 63;
    const int wid  = tid >> 6;
    int bid = blockIdx.x;
    const int p  = bid & 31; bid >>= 5;
    const int qb = bid & 3;  bid >>= 2;
    const int h  = bid;
    const int col = lane & 31;
    const int hi  = lane >> 5;
    const int n0  = qb * 256 + wid * 64 + col;
    const int n1  = n0 + 32;

    bf16x8 qA[4], qB[4];
    {
        const int b0 = n0 >> 9, s0 = n0 & 511;
        const int b1 = n1 >> 9, s1 = n1 & 511;
        const float* qp0 = query + ((((size_t)b0 * NHEADS + h) * SEQ + s0) << 6);
        const float* qp1 = query + ((((size_t)b1 * NHEADS + h) * SEQ + s1) << 6);
#pragma unroll
        for (int ks = 0; ks < 4; ++ks) {
            const int d0 = ks * 16 + hi * 8;
            qA[ks] = pack8f(*(const float4*)(qp0 + d0), *(const float4*)(qp0 + d0 + 4));
            qB[ks] = pack8f(*(const float4*)(qp1 + d0), *(const float4*)(qp1 + d0 + 4));
        }
    }

    const f32x16 z16 = {0,0,0,0,0,0,0,0,0,0,0,0,0,0,0,0};
    float gA = -1e30f, gB = -1e30f;

    const unsigned char* gsrc = (const unsigned char*)kbf
        + ((size_t)h * 512 + (size_t)p * NT) * 4096;

    STAGE(0);
    __syncthreads();
#pragma unroll 1
    for (int c = 0; c < NCHUNK; ++c) {
        if (c + 1 < NCHUNK) STAGE(c + 1);
        const unsigned char* base = &lds[c & 1][0];
#pragma unroll
        for (int t = 0; t < CHT; ++t) {
            const unsigned char* tb = base + t * 4096 + lane * 16;
            bf16x8 a0 = *(const bf16x8*)(tb);
            bf16x8 a1 = *(const bf16x8*)(tb + 1024);
            bf16x8 a2 = *(const bf16x8*)(tb + 2048);
            bf16x8 a3 = *(const bf16x8*)(tb + 3072);
            MFMA8Z(accA, accB, a0, a1, a2, a3)
            gA = fmaxf(gA, max16v(accA));
            gB = fmaxf(gB, max16v(accB));
        }
        __syncthreads();
    }

    pmax[(((size_t)h * NQ + n0) << 6) + p * 2 + hi] = gA;
    pmax[(((size_t)h * NQ + n1) << 6) + p * 2 + hi] = gB;
}

// ---------------------------------------------------------------------------
// Kernel 3 (taured): per query, exact 8th-largest of its 64 group maxes.
// Each group max is a real value of that query, so tau_q <= v8: superset-safe.
// ---------------------------------------------------------------------------
__global__ __launch_bounds__(256)
void taured_kernel(const float* __restrict__ pmax,
                   float* __restrict__ tauv) {
    const int gid = blockIdx.x * 256 + threadIdx.x;   // query id h*NQ+n
    float tv[8];
#pragma unroll
    for (int j = 0; j < 8; ++j) tv[j] = -1e30f;
#pragma unroll
    for (int k = 0; k < NGRP; ++k) ins8(tv, pmax[((size_t)gid << 6) + k]);
    tauv[gid] = tv[7];
}

// ---------------------------------------------------------------------------
// Kernel 4 (scanB): MFMA pass 2, same LDS sharing. Emit mem indices with
// bf16-score >= tau_q - margin_q (margin = 2*2^-8*||q|| + 0.01 covers bf16
// rounding of both operands -> emitted set provably contains the fp32
// top-8). Emission gated behind per-lane tile max.
// ---------------------------------------------------------------------------
__global__ __launch_bounds__(256, 6)
void scanB_kernel(const float* __restrict__ query,
                  const unsigned short* __restrict__ kbf,
                  const float* __restrict__ tauv,
                  unsigned* __restrict__ pcand,
                  unsigned* __restrict__ pcnt) {
    __shared__ __align__(16) unsigned char lds[2][CHT * 4096];
    const int tid  = threadIdx.x;
    const int lane = tid & 63;
    const int wid  = tid >> 6;
    int bid = blockIdx.x;
    const int p  = bid & 31; bid >>= 5;
    const int qb = bid & 3;  bid >>= 2;
    const int h  = bid;
    const int col = lane & 31;
    const int hi  = lane >> 5;
    const int n0  = qb * 256 + wid * 64 + col;
    const int n1  = n0 + 32;

    bf16x8 qA[4], qB[4];
    float ssA = 0.f, ssB = 0.f;
    {
        const int b0 = n0 >> 9, s0 = n0 & 511;
        const int b1 = n1 >> 9, s1 = n1 & 511;
        const float* qp0 = query + ((((size_t)b0 * NHEADS + h) * SEQ + s0) << 6);
        const float* qp1 = query + ((((size_t)b1 * NHEADS + h) * SEQ + s1) << 6);
#pragma unroll
        for (int ks = 0; ks < 4; ++ks) {
            const int d0 = ks * 16 + hi * 8;
            float4 a0 = *(const float4*)(qp0 + d0), b0v = *(const float4*)(qp0 + d0 + 4);
            float4 a1 = *(const float4*)(qp1 + d0), b1v = *(const float4*)(qp1 + d0 + 4);
            ssA += SS(a0) + SS(b0v);
            ssB += SS(a1) + SS(b1v);
            qA[ks] = pack8f(a0, b0v);
            qB[ks] = pack8f(a1, b1v);
        }
    }
    ssA += __shfl_xor(ssA, 32);   // other half's dims (same query)
    ssB += __shfl_xor(ssB, 32);
    const float tA = tauv[h * NQ + n0] - (sqrtf(ssA) * 0.0078125f + 0.01f);
    const float tB = tauv[h * NQ + n1] - (sqrtf(ssB) * 0.0078125f + 0.01f);

    const f32x16 z16 = {0,0,0,0,0,0,0,0,0,0,0,0,0,0,0,0};

    const unsigned char* gsrc = (const unsigned char*)kbf
        + ((size_t)h * 512 + (size_t)p * NT) * 4096;

    unsigned cA = 0, cB = 0;
    const size_t chA = (((size_t)h * NQ + n0) << 6) + p * 2 + hi;
    const size_t chB = (((size_t)h * NQ + n1) << 6) + p * 2 + hi;
    unsigned* mApt = pcand + chA * CMAX;
    unsigned* mBpt = pcand + chB * CMAX;

#define EMITG(ACC, TAU, C, LST, MBV) do {                                     \
        const float _g = max16v(ACC);                                         \
        if (_g >= (TAU)) {                                                    \
            unsigned _msk = 0;                                                \
            _Pragma("unroll")                                                 \
            for (int _r = 0; _r < 16; ++_r)                                   \
                _msk |= (ACC[_r] >= (TAU)) ? (1u << _r) : 0u;                 \
            do {                                                              \
                int _r = __ffs(_msk) - 1;                                     \
                unsigned _idx = (unsigned)((MBV) + (_r & 3) + 8 * (_r >> 2)); \
                if ((C) < CMAX) (LST)[C] = _idx;                              \
                ++(C);                                                        \
                _msk &= _msk - 1;                                             \
            } while (_msk);                                                   \
        }                                                                     \
    } while (0)

    STAGE(0);
    __syncthreads();
#pragma unroll 1
    for (int c = 0; c < NCHUNK; ++c) {
        if (c + 1 < NCHUNK) STAGE(c + 1);
        const unsigned char* base = &lds[c & 1][0];
#pragma unroll
        for (int t = 0; t < CHT; ++t) {
            const unsigned char* tb = base + t * 4096 + lane * 16;
            bf16x8 a0 = *(const bf16x8*)(tb);
            bf16x8 a1 = *(const bf16x8*)(tb + 1024);
            bf16x8 a2 = *(const bf16x8*)(tb + 2048);
            bf16x8 a3 = *(const bf16x8*)(tb + 3072);
            MFMA8Z(accA, accB, a0, a1, a2, a3)
            const int mbv = p * (NT * 32) + (c * CHT + t) * 32 + 4 * hi;
            EMITG(accA, tA, cA, mApt, mbv);
            EMITG(accB, tB, cB, mBpt, mbv);
        }
        __syncthreads();
    }
    pcnt[chA] = cA;
    pcnt[chB] = cB;
#undef EMITG
}

// ---------------------------------------------------------------------------
// Kernel 5 (rescore_merge): one wave per query. Lane d4=lane&15 holds the
// query float4; candidate dot = per-lane partial + 4 shfl_xor. Exact top-8
// via packed u64 keys (monotone(score)<<32 | ~idx): order = (score desc,
// idx asc), branchless ins8u64, bit-exact score recovery. V-gather: lane i
// owns output element i. Overflow -> exact full-memory loop.
// 64 candidate groups map 1:1 onto the 64 lanes for the prefix-scan compact.
// ---------------------------------------------------------------------------
__global__ __launch_bounds__(64, 8)
void rescore_merge_kernel(const float* __restrict__ query,
                          const float* __restrict__ kmem,
                          const float* __restrict__ knr,
                          const unsigned* __restrict__ pcand,
                          const unsigned* __restrict__ pcnt,
                          const float* __restrict__ vmem,
                          const float* __restrict__ outputs,
                          const float* __restrict__ gate,
                          float* __restrict__ out) {
    __shared__ unsigned cands[NGRP * CMAX];
    const int gid = blockIdx.x;            // query id
    const int h = gid >> 10;
    const int n = gid & 1023;
    const int b = n >> 9;
    const int s = n & 511;
    const int lane = threadIdx.x;
    const int d4 = lane & 15;

    const float* qbase = query + ((((size_t)b * NHEADS + h) * SEQ + s) << 6);
    const float4 q4 = ((const float4*)qbase)[d4];
    float ssp = SS(q4);
    ssp += __shfl_xor(ssp, 1);
    ssp += __shfl_xor(ssp, 2);
    ssp += __shfl_xor(ssp, 4);
    ssp += __shfl_xor(ssp, 8);     // full ||q||^2 within each 16-lane group
    const float qs = 1.0f / (fmaxf(sqrtf(ssp), EPS) * 8.0f);

    // compact the 64 candidate lists into LDS (full-wave shfl prefix scan)
    const unsigned cg = pcnt[((size_t)gid << 6) + lane];
    const bool anyovf = (__ballot(cg > CMAX) != 0ULL);
    unsigned inc = cg;
#pragma unroll
    for (int d = 1; d < 64; d <<= 1) {
        unsigned t = __shfl_up(inc, d, 64);
        if (lane >= d) inc += t;
    }
    const unsigned ct = __shfl(inc, 63, 64);
    const unsigned excl = inc - cg;
    {
        const unsigned* lp = pcand + (((size_t)gid << 6) + lane) * CMAX;
        const unsigned cc = cg > CMAX ? CMAX : cg;
        for (unsigned c = 0; c < cc; ++c) cands[excl + c] = lp[c];
    }
    __syncthreads();

    const float* kb = kmem + ((size_t)h << 20);
    const float* nb = knr + h * MMEM;

    unsigned long long top[8];
#pragma unroll
    for (int j = 0; j < 8; ++j) top[j] = 0ULL;

#define SCORE_KEY(IDX) ({                                                     \
        float4 kv = ((const float4*)(kb + ((size_t)(IDX) << 6)))[d4];         \
        float d = q4.x*kv.x + q4.y*kv.y + q4.z*kv.z + q4.w*kv.w;              \
        d += __shfl_xor(d, 1);                                                \
        d += __shfl_xor(d, 2);                                                \
        d += __shfl_xor(d, 4);                                                \
        d += __shfl_xor(d, 8);                                                \
        const float sc = d * qs * nb[IDX];                                    \
        unsigned su = __builtin_bit_cast(unsigned, sc);                       \
        unsigned ms = su ^ ((su >> 31) ? 0xFFFFFFFFu : 0x80000000u);          \
        ((unsigned long long)ms << 32) | (0xFFFFFFFFu - (unsigned)(IDX));     \
    })

    if (!anyovf) {
#pragma unroll 1
        for (unsigned c = 0; c < ct; ++c) {
            const unsigned idx = cands[c];
            ins8u64(top, SCORE_KEY(idx));
        }
    } else {
        // exact fallback: all memories (practically never taken)
#pragma unroll 1
        for (int m = 0; m < MMEM; ++m) ins8u64(top, SCORE_KEY(m));
    }
#undef SCORE_KEY

    // V-gather + gate blend: lane owns output element `lane`
    float acc = 0.0f;
    const float* vb = vmem + ((size_t)h << 20);
#pragma unroll
    for (int j = 0; j < 8; ++j) {
        const unsigned long long key = top[j];
        const unsigned idx = 0xFFFFFFFFu - (unsigned)(key & 0xFFFFFFFFu);
        const unsigned ms = (unsigned)(key >> 32);
        const unsigned su = ms ^ ((ms >> 31) ? 0x80000000u : 0xFFFFFFFFu);
        const float sc = __builtin_bit_cast(float, su);
        acc = fmaf(sc, vb[((size_t)idx << 6) + lane], acc);
    }

    const float gg = 1.0f / (1.0f + expf(-gate[h]));
    const size_t off = ((((size_t)b * NHEADS + h) * SEQ + s) << 6) + lane;
    out[off] = gg * acc + (1.0f - gg) * outputs[off];
}

// ---------------------------------------------------------------------------
// Fallback path (ws too small): fp32 scan + merge (previous rounds').
// ---------------------------------------------------------------------------
__global__ void knorm_kernel(const float* __restrict__ kmem,
                             float* __restrict__ knr) {
    int gid = blockIdx.x * 256 + threadIdx.x;
    int mem = gid >> 4;
    int d4  = gid & 15;
    float4 kv = reinterpret_cast<const float4*>(kmem)[(size_t)mem * 16 + d4];
    float ss = SS(kv);
    ss += __shfl_xor(ss, 1);
    ss += __shfl_xor(ss, 2);
    ss += __shfl_xor(ss, 4);
    ss += __shfl_xor(ss, 8);
    if (d4 == 0) knr[mem] = 1.0f / fmaxf(sqrtf(ss), EPS);
}

__global__ __launch_bounds__(64, 4)
void scan_kernel(const float* __restrict__ query,
                 const float* __restrict__ kmem,
                 const float* __restrict__ knr,
                 float* __restrict__ pscore,
                 int* __restrict__ pidx,
                 int P, int CH) {
    const int lane = threadIdx.x & 63;
    int bid = blockIdx.x;
    const int p  = bid % P;  bid /= P;
    const int qb = bid & 15; bid >>= 4;
    const int h  = bid;
    const int n  = qb * 64 + lane;
    const int b  = n >> 9;
    const int s  = n & 511;

    const float4* qp = reinterpret_cast<const float4*>(
        query + (((size_t)b * NHEADS + h) * SEQ + s) * HD);
    float q[HD];
    float ss = 0.0f;
#pragma unroll
    for (int i = 0; i < 16; ++i) {
        float4 v = qp[i];
        q[4*i+0] = v.x; q[4*i+1] = v.y; q[4*i+2] = v.z; q[4*i+3] = v.w;
        ss += SS(v);
    }
    const float rq = 1.0f / (fmaxf(sqrtf(ss), EPS) * 8.0f);
#pragma unroll
    for (int i = 0; i < HD; ++i) q[i] *= rq;

    float tv[8]; int ti[8];
#pragma unroll
    for (int j = 0; j < 8; ++j) { tv[j] = -INFINITY; ti[j] = 0; }

    const int m0 = p * CH;
    const float4* kp = reinterpret_cast<const float4*>(
        kmem + ((size_t)h * MMEM + m0) * HD);
    const float* knrp = knr + h * MMEM + m0;

    for (int mm = 0; mm < CH; ++mm) {
        float d0 = 0.f, d1 = 0.f, d2 = 0.f, d3 = 0.f;
#pragma unroll
        for (int i = 0; i < 16; ++i) {
            float4 kv = kp[(size_t)mm * 16 + i];
            d0 = fmaf(q[4*i+0], kv.x, d0);
            d1 = fmaf(q[4*i+1], kv.y, d1);
            d2 = fmaf(q[4*i+2], kv.z, d2);
            d3 = fmaf(q[4*i+3], kv.w, d3);
        }
        const float sim = ((d0 + d1) + (d2 + d3)) * knrp[mm];
        if (sim > tv[7]) {
            tv[7] = sim; ti[7] = m0 + mm;
#pragma unroll
            for (int j = 7; j > 0; --j) {
                if (tv[j] > tv[j-1]) {
                    float tf = tv[j]; tv[j] = tv[j-1]; tv[j-1] = tf;
                    int   tu = ti[j]; ti[j] = ti[j-1]; ti[j-1] = tu;
                }
            }
        }
    }

    const size_t base = (((size_t)h * NQ + n) * P + p) * 8;
#pragma unroll
    for (int j = 0; j < 8; ++j) { pscore[base+j] = tv[j]; pidx[base+j] = ti[j]; }
}

__global__ void merge_kernel(const float* __restrict__ pscore,
                             const int* __restrict__ pidx,
                             const float* __restrict__ vmem,
                             const float* __restrict__ outputs,
                             const float* __restrict__ gate,
                             float* __restrict__ out, int P) {
    const int t = blockIdx.x * 256 + threadIdx.x;
    const int h = t >> 10;
    const int n = t & 1023;
    const int b = n >> 9;
    const int s = n & 511;

    float tv[8]; int ti[8];
    const size_t base = ((size_t)h * NQ + n) * P * 8;
#pragma unroll
    for (int j = 0; j < 8; ++j) { tv[j] = pscore[base + j]; ti[j] = pidx[base + j]; }
    const int total = P * 8;
    for (int c = 8; c < total; ++c) {
        const float v = pscore[base + c];
        if (v > tv[7]) {
            tv[7] = v; ti[7] = pidx[base + c];
#pragma unroll
            for (int j = 7; j > 0; --j) {
                if (tv[j] > tv[j-1]) {
                    float tf = tv[j]; tv[j] = tv[j-1]; tv[j-1] = tf;
                    int   tu = ti[j]; ti[j] = ti[j-1]; ti[j-1] = tu;
                }
            }
        }
    }

    float4 acc[16];
#pragma unroll
    for (int i = 0; i < 16; ++i) acc[i] = make_float4(0.f, 0.f, 0.f, 0.f);
#pragma unroll
    for (int j = 0; j < 8; ++j) {
        const float4* vp = reinterpret_cast<const float4*>(
            vmem + ((size_t)h * MMEM + ti[j]) * HD);
        const float sc = tv[j];
#pragma unroll
        for (int i = 0; i < 16; ++i) {
            float4 v = vp[i];
            acc[i].x = fmaf(sc, v.x, acc[i].x);
            acc[i].y = fmaf(sc, v.y, acc[i].y);
            acc[i].z = fmaf(sc, v.z, acc[i].z);
            acc[i].w = fmaf(sc, v.w, acc[i].w);
        }
    }

    const float g  = 1.0f / (1.0f + expf(-gate[h]));
    const float og = 1.0f - g;
    const size_t off = (((size_t)b * NHEADS + h) * SEQ + s) * HD;
    const float4* op = reinterpret_cast<const float4*>(outputs + off);
    float4* dst = reinterpret_cast<float4*>(out + off);
#pragma unroll
    for (int i = 0; i < 16; ++i) {
        float4 o = op[i];
        float4 r;
        r.x = g * acc[i].x + og * o.x;
        r.y = g * acc[i].y + og * o.y;
        r.z = g * acc[i].z + og * o.z;
        r.w = g * acc[i].w + og * o.w;
        dst[i] = r;
    }
}

// ---------------------------------------------------------------------------
extern "C" void kernel_launch(void* const* d_in, const int* in_sizes, int n_in,
                              void* d_out, int out_size, void* d_ws, size_t ws_size,
                              hipStream_t stream) {
    const float* query   = (const float*)d_in[1];
    const float* outputs = (const float*)d_in[4];
    const float* gate    = (const float*)d_in[5];
    const float* kmem    = (const float*)d_in[6];
    const float* vmem    = (const float*)d_in[7];
    float* out = (float*)d_out;

    const size_t NQTOT    = (size_t)NHEADS * NQ;                 // 16384 queries
    const size_t sz_knr   = (size_t)NHEADS * MMEM * 4;           //  1.0 MB
    const size_t sz_kbf   = (size_t)NHEADS * MMEM * HD * 2;      // 33.5 MB
    const size_t sz_pmax  = NQTOT * NGRP * 4;                    //  4.2 MB
    const size_t sz_tauv  = NQTOT * 4;                           //  0.07 MB
    const size_t sz_pcand = NQTOT * NGRP * CMAX * 4;             // 16.8 MB
    const size_t sz_pcnt  = NQTOT * NGRP * 4;                    //  4.2 MB
    const size_t need = sz_knr + sz_kbf + sz_pmax + sz_tauv + sz_pcand + sz_pcnt;

    if (ws_size >= need) {
        char* w = (char*)d_ws;
        float*          knr   = (float*)w;          w += sz_knr;
        unsigned short* kbf   = (unsigned short*)w; w += sz_kbf;
        float*          pmax  = (float*)w;          w += sz_pmax;
        float*          tauv  = (float*)w;          w += sz_tauv;
        unsigned*       pcand = (unsigned*)w;       w += sz_pcand;
        unsigned*       pcnt  = (unsigned*)w;

        kprep_kernel<<<(NHEADS * 512 * 4 * 64) / 256, 256, 0, stream>>>(kmem, knr, kbf);
        scanA_kernel<<<NHEADS * 4 * NPART, 256, 0, stream>>>(query, kbf, pmax);
        taured_kernel<<<(int)(NQTOT / 256), 256, 0, stream>>>(pmax, tauv);
        scanB_kernel<<<NHEADS * 4 * NPART, 256, 0, stream>>>(query, kbf, tauv, pcand, pcnt);
        rescore_merge_kernel<<<(int)NQTOT, 64, 0, stream>>>(
            query, kmem, knr, pcand, pcnt, vmem, outputs, gate, out);
    } else {
        int P = 16;
        while (P > 4 &&
               (size_t)NHEADS * MMEM * 4 + (size_t)NHEADS * NQ * (size_t)P * 64 > ws_size)
            P >>= 1;
        const int CH = MMEM / P;

        float* knr    = (float*)d_ws;
        float* pscore = knr + (size_t)NHEADS * MMEM;
        int*   pidx   = (int*)(pscore + (size_t)NHEADS * NQ * (size_t)P * 8);

        knorm_kernel<<<(NHEADS * MMEM * 16) / 256, 256, 0, stream>>>(kmem, knr);
        scan_kernel<<<NHEADS * 16 * P, 64, 0, stream>>>(
            query, kmem, knr, pscore, pidx, P, CH);
        merge_kernel<<<(NHEADS * NQ) / 256, 256, 0, stream>>>(
            pscore, pidx, vmem, outputs, gate, out, P);
    }
}

// Round 17
// 145.467 us; speedup vs baseline: 55.5069x; 55.5069x over previous
//
#include <hip/hip_runtime.h>
#include <math.h>

#define NHEADS 16
#define HD 64
#define MMEM 16384
#define NQ 1024   // B*S per head
#define SEQ 512
#define EPS 1e-8f
#define NPART 16
#define NT 32     // 32-mem tiles per partition (16384/16/32)
#define NGRP 32   // candidate groups per query: NPART * 2 halves
#define CMAX 8    // candidate slots per (query, group)
#define CHT 4     // tiles per staged chunk (16 KB)
#define NCHUNK 8  // chunks per partition

typedef short bf16x8 __attribute__((ext_vector_type(8)));
typedef float f32x16 __attribute__((ext_vector_type(16)));

typedef const __attribute__((address_space(1))) unsigned int* gas_u32p;
typedef __attribute__((address_space(3))) unsigned int* las_u32p;

__device__ inline unsigned short f2bf(float f) {
    unsigned int u = __builtin_bit_cast(unsigned int, f);
    unsigned int r = (u + 0x7FFFu + ((u >> 16) & 1u)) >> 16;  // RNE
    return (unsigned short)r;
}

#define SS(Q) (Q.x*Q.x + Q.y*Q.y + Q.z*Q.z + Q.w*Q.w)

// ---------------------------------------------------------------------------
// Kernel 1: fused knorm + kprep. Block = one (h,tile): 32 rows x 64 d,
// 4 ks-slices. Row 1/||k|| via one LDS round; writes knr AND normalized bf16
// keys in MFMA-A tile order:
// (((h*512+t)*4+ks)*64+lane)*8 elems = kmem[h][t*32+(lane&31)][ks*16+(lane>>5)*8+j]*rn.
// ---------------------------------------------------------------------------
__global__ __launch_bounds__(256)
void kprep_kernel(const float* __restrict__ kmem,
                  float* __restrict__ knr,
                  unsigned short* __restrict__ kbf) {
    __shared__ float ssl[256];
    const int tid = threadIdx.x;
    const int gid = blockIdx.x * 256 + tid;
    const int lane = gid & 63;
    const int ks   = (gid >> 6) & 3;
    const int t    = (gid >> 8) & 511;
    const int h    = gid >> 17;
    const int r    = lane & 31;
    const int hi   = lane >> 5;
    const int row  = t * 32 + r;
    const int d0   = ks * 16 + hi * 8;

    const float* src = kmem + (((size_t)h * MMEM + row) << 6) + d0;
    float4 v0 = *(const float4*)(src);
    float4 v1 = *(const float4*)(src + 4);
    ssl[tid] = SS(v0) + SS(v1);      // tid = ks*64 + hi*32 + r
    __syncthreads();
    float tot = ssl[r +   0] + ssl[r +  32] + ssl[r +  64] + ssl[r +  96]
              + ssl[r + 128] + ssl[r + 160] + ssl[r + 192] + ssl[r + 224];
    const float rn = 1.0f / fmaxf(sqrtf(tot), EPS);
    if (tid < 32) knr[h * MMEM + row] = rn;

    uint4 o;
    o.x = (unsigned)f2bf(v0.x * rn) | ((unsigned)f2bf(v0.y * rn) << 16);
    o.y = (unsigned)f2bf(v0.z * rn) | ((unsigned)f2bf(v0.w * rn) << 16);
    o.z = (unsigned)f2bf(v1.x * rn) | ((unsigned)f2bf(v1.y * rn) << 16);
    o.w = (unsigned)f2bf(v1.z * rn) | ((unsigned)f2bf(v1.w * rn) << 16);
    *(uint4*)(kbf + (size_t)gid * 8) = o;
}

// ---------------------------------------------------------------------------
// Shared scan helpers
// ---------------------------------------------------------------------------
__device__ inline float max16v(const f32x16& a) {
    float m0 = fmaxf(fmaxf(a[0],  a[1]),  a[2]);
    float m1 = fmaxf(fmaxf(a[3],  a[4]),  a[5]);
    float m2 = fmaxf(fmaxf(a[6],  a[7]),  a[8]);
    float m3 = fmaxf(fmaxf(a[9],  a[10]), a[11]);
    float m4 = fmaxf(fmaxf(a[12], a[13]), a[14]);
    float n0 = fmaxf(fmaxf(m0, m1), m2);
    float n1 = fmaxf(fmaxf(m3, m4), a[15]);
    return fmaxf(n0, n1);
}

__device__ inline void ins8(float (&tv)[8], float v) {
#pragma unroll
    for (int j = 0; j < 8; ++j) {
        float h_ = fmaxf(tv[j], v);
        float l_ = fminf(tv[j], v);
        tv[j] = h_;
        v = l_;
    }
}

__device__ inline void ins8u64(unsigned long long (&tv)[8], unsigned long long v) {
#pragma unroll
    for (int j = 0; j < 8; ++j) {
        unsigned long long h_ = tv[j] > v ? tv[j] : v;
        unsigned long long l_ = tv[j] > v ? v : tv[j];
        tv[j] = h_;
        v = l_;
    }
}

__device__ inline bf16x8 pack8f(float4 a, float4 b) {
    bf16x8 f;
    f[0] = (short)f2bf(a.x); f[1] = (short)f2bf(a.y);
    f[2] = (short)f2bf(a.z); f[3] = (short)f2bf(a.w);
    f[4] = (short)f2bf(b.x); f[5] = (short)f2bf(b.y);
    f[6] = (short)f2bf(b.z); f[7] = (short)f2bf(b.w);
    return f;
}

// two query-groups per tile, both accs seeded from loop-invariant zero C
#define MFMA8Z(ACCA, ACCB, A0, A1, A2, A3)                                    \
    f32x16 ACCA = __builtin_amdgcn_mfma_f32_32x32x16_bf16(A0, qA[0], z16, 0,0,0); \
    f32x16 ACCB = __builtin_amdgcn_mfma_f32_32x32x16_bf16(A0, qB[0], z16, 0,0,0); \
    ACCA = __builtin_amdgcn_mfma_f32_32x32x16_bf16(A1, qA[1], ACCA, 0, 0, 0); \
    ACCB = __builtin_amdgcn_mfma_f32_32x32x16_bf16(A1, qB[1], ACCB, 0, 0, 0); \
    ACCA = __builtin_amdgcn_mfma_f32_32x32x16_bf16(A2, qA[2], ACCA, 0, 0, 0); \
    ACCB = __builtin_amdgcn_mfma_f32_32x32x16_bf16(A2, qB[2], ACCB, 0, 0, 0); \
    ACCA = __builtin_amdgcn_mfma_f32_32x32x16_bf16(A3, qA[3], ACCA, 0, 0, 0); \
    ACCB = __builtin_amdgcn_mfma_f32_32x32x16_bf16(A3, qB[3], ACCB, 0, 0, 0);

// stage one 16 KB chunk (4 tiles) into lds buffer via global_load_lds
#define STAGE(CH) do {                                                        \
        const unsigned char* _s = gsrc + (size_t)(CH) * (CHT * 4096);         \
        unsigned char* _d = &lds[(CH) & 1][0];                                \
        _Pragma("unroll")                                                     \
        for (int _j = 0; _j < CHT; ++_j)                                      \
            __builtin_amdgcn_global_load_lds(                                 \
                (gas_u32p)(const void*)(_s + _j * 4096 + tid * 16),           \
                (las_u32p)(void*)(_d + _j * 4096 + tid * 16), 16, 0, 0);      \
    } while (0)

// ---------------------------------------------------------------------------
// Kernel 2 (scanA): MFMA pass 1 with multi-wave LDS tile sharing (validated
// R13/R15 form: plain __syncthreads double-buffering — STAGE(c+1) issued
// before compute so the barrier drain usually finds loads complete).
// Block = 4 waves x 64 queries = 256 queries x one partition (1024 mems).
// Selection = one running fmax per (query, half) -> pmax[q][p*2+hi].
// D-layout: col=lane&31 (query), row=(reg&3)+8*(reg>>2)+4*(lane>>5) (mem).
// ---------------------------------------------------------------------------
__global__ __launch_bounds__(256, 4)
void scanA_kernel(const float* __restrict__ query,
                  const unsigned short* __restrict__ kbf,
                  float* __restrict__ pmax) {
    __shared__ __align__(16) unsigned char lds[2][CHT * 4096];
    const int tid  = threadIdx.x;
    const int lane = tid & 63;
    const int wid  = tid >> 6;
    int bid = blockIdx.x;
    const int p  = bid & 15; bid >>= 4;
    const int qb = bid & 3;  bid >>= 2;
    const int h  = bid;
    const int col = lane & 31;
    const int hi  = lane >> 5;
    const int n0  = qb * 256 + wid * 64 + col;
    const int n1  = n0 + 32;

    bf16x8 qA[4], qB[4];
    {
        const int b0 = n0 >> 9, s0 = n0 & 511;
        const int b1 = n1 >> 9, s1 = n1 & 511;
        const float* qp0 = query + ((((size_t)b0 * NHEADS + h) * SEQ + s0) << 6);
        const float* qp1 = query + ((((size_t)b1 * NHEADS + h) * SEQ + s1) << 6);
#pragma unroll
        for (int ks = 0; ks < 4; ++ks) {
            const int d0 = ks * 16 + hi * 8;
            qA[ks] = pack8f(*(const float4*)(qp0 + d0), *(const float4*)(qp0 + d0 + 4));
            qB[ks] = pack8f(*(const float4*)(qp1 + d0), *(const float4*)(qp1 + d0 + 4));
        }
    }

    const f32x16 z16 = {0,0,0,0,0,0,0,0,0,0,0,0,0,0,0,0};
    float gA = -1e30f, gB = -1e30f;

    const unsigned char* gsrc = (const unsigned char*)kbf
        + ((size_t)h * 512 + (size_t)p * NT) * 4096;

    STAGE(0);
    __syncthreads();
#pragma unroll 1
    for (int c = 0; c < NCHUNK; ++c) {
        if (c + 1 < NCHUNK) STAGE(c + 1);
        const unsigned char* base = &lds[c & 1][0];
        __builtin_amdgcn_s_setprio(1);
#pragma unroll
        for (int t = 0; t < CHT; ++t) {
            const unsigned char* tb = base + t * 4096 + lane * 16;
            bf16x8 a0 = *(const bf16x8*)(tb);
            bf16x8 a1 = *(const bf16x8*)(tb + 1024);
            bf16x8 a2 = *(const bf16x8*)(tb + 2048);
            bf16x8 a3 = *(const bf16x8*)(tb + 3072);
            MFMA8Z(accA, accB, a0, a1, a2, a3)
            gA = fmaxf(gA, max16v(accA));
            gB = fmaxf(gB, max16v(accB));
        }
        __builtin_amdgcn_s_setprio(0);
        __syncthreads();
    }

    pmax[(((size_t)h * NQ + n0) << 5) + p * 2 + hi] = gA;
    pmax[(((size_t)h * NQ + n1) << 5) + p * 2 + hi] = gB;
}

// ---------------------------------------------------------------------------
// Kernel 3 (taured): per query, exact 8th-largest of its 32 group maxes.
// Each group max is a real value of that query, so tau_q <= v8: superset-safe.
// ---------------------------------------------------------------------------
__global__ __launch_bounds__(256)
void taured_kernel(const float* __restrict__ pmax,
                   float* __restrict__ tauv) {
    const int gid = blockIdx.x * 256 + threadIdx.x;   // query id h*NQ+n
    float tv[8];
#pragma unroll
    for (int j = 0; j < 8; ++j) tv[j] = -1e30f;
#pragma unroll
    for (int k = 0; k < NGRP; ++k) ins8(tv, pmax[((size_t)gid << 5) + k]);
    tauv[gid] = tv[7];
}

// ---------------------------------------------------------------------------
// Kernel 4 (scanB): MFMA pass 2 with the same LDS tile sharing + setprio.
// Emit mem indices with bf16-score >= tau_q - margin_q (margin =
// 2*2^-8*||q|| + 0.01 covers bf16 rounding of both operands -> emitted set
// provably contains the fp32 top-8). Emission gated behind per-lane tile max.
// ---------------------------------------------------------------------------
__global__ __launch_bounds__(256, 4)
void scanB_kernel(const float* __restrict__ query,
                  const unsigned short* __restrict__ kbf,
                  const float* __restrict__ tauv,
                  unsigned* __restrict__ pcand,
                  unsigned* __restrict__ pcnt) {
    __shared__ __align__(16) unsigned char lds[2][CHT * 4096];
    const int tid  = threadIdx.x;
    const int lane = tid & 63;
    const int wid  = tid >> 6;
    int bid = blockIdx.x;
    const int p  = bid & 15; bid >>= 4;
    const int qb = bid & 3;  bid >>= 2;
    const int h  = bid;
    const int col = lane & 31;
    const int hi  = lane >> 5;
    const int n0  = qb * 256 + wid * 64 + col;
    const int n1  = n0 + 32;

    bf16x8 qA[4], qB[4];
    float ssA = 0.f, ssB = 0.f;
    {
        const int b0 = n0 >> 9, s0 = n0 & 511;
        const int b1 = n1 >> 9, s1 = n1 & 511;
        const float* qp0 = query + ((((size_t)b0 * NHEADS + h) * SEQ + s0) << 6);
        const float* qp1 = query + ((((size_t)b1 * NHEADS + h) * SEQ + s1) << 6);
#pragma unroll
        for (int ks = 0; ks < 4; ++ks) {
            const int d0 = ks * 16 + hi * 8;
            float4 a0 = *(const float4*)(qp0 + d0), b0v = *(const float4*)(qp0 + d0 + 4);
            float4 a1 = *(const float4*)(qp1 + d0), b1v = *(const float4*)(qp1 + d0 + 4);
            ssA += SS(a0) + SS(b0v);
            ssB += SS(a1) + SS(b1v);
            qA[ks] = pack8f(a0, b0v);
            qB[ks] = pack8f(a1, b1v);
        }
    }
    ssA += __shfl_xor(ssA, 32);   // other half's dims (same query)
    ssB += __shfl_xor(ssB, 32);
    const float tA = tauv[h * NQ + n0] - (sqrtf(ssA) * 0.0078125f + 0.01f);
    const float tB = tauv[h * NQ + n1] - (sqrtf(ssB) * 0.0078125f + 0.01f);

    const f32x16 z16 = {0,0,0,0,0,0,0,0,0,0,0,0,0,0,0,0};

    const unsigned char* gsrc = (const unsigned char*)kbf
        + ((size_t)h * 512 + (size_t)p * NT) * 4096;

    unsigned cA = 0, cB = 0;
    const size_t chA = (((size_t)h * NQ + n0) << 5) + p * 2 + hi;
    const size_t chB = (((size_t)h * NQ + n1) << 5) + p * 2 + hi;
    unsigned* mApt = pcand + chA * CMAX;
    unsigned* mBpt = pcand + chB * CMAX;

#define EMITG(ACC, TAU, C, LST, MBV) do {                                     \
        const float _g = max16v(ACC);                                         \
        if (_g >= (TAU)) {                                                    \
            unsigned _msk = 0;                                                \
            _Pragma("unroll")                                                 \
            for (int _r = 0; _r < 16; ++_r)                                   \
                _msk |= (ACC[_r] >= (TAU)) ? (1u << _r) : 0u;                 \
            do {                                                              \
                int _r = __ffs(_msk) - 1;                                     \
                unsigned _idx = (unsigned)((MBV) + (_r & 3) + 8 * (_r >> 2)); \
                if ((C) < CMAX) (LST)[C] = _idx;                              \
                ++(C);                                                        \
                _msk &= _msk - 1;                                             \
            } while (_msk);                                                   \
        }                                                                     \
    } while (0)

    STAGE(0);
    __syncthreads();
#pragma unroll 1
    for (int c = 0; c < NCHUNK; ++c) {
        if (c + 1 < NCHUNK) STAGE(c + 1);
        const unsigned char* base = &lds[c & 1][0];
        __builtin_amdgcn_s_setprio(1);
#pragma unroll
        for (int t = 0; t < CHT; ++t) {
            const unsigned char* tb = base + t * 4096 + lane * 16;
            bf16x8 a0 = *(const bf16x8*)(tb);
            bf16x8 a1 = *(const bf16x8*)(tb + 1024);
            bf16x8 a2 = *(const bf16x8*)(tb + 2048);
            bf16x8 a3 = *(const bf16x8*)(tb + 3072);
            MFMA8Z(accA, accB, a0, a1, a2, a3)
            const int mbv = p * 1024 + (c * CHT + t) * 32 + 4 * hi;
            EMITG(accA, tA, cA, mApt, mbv);
            EMITG(accB, tB, cB, mBpt, mbv);
        }
        __builtin_amdgcn_s_setprio(0);
        __syncthreads();
    }
    pcnt[chA] = cA;
    pcnt[chB] = cB;
#undef EMITG
}

// ---------------------------------------------------------------------------
// Kernel 5 (rescore_merge): one wave per query. Lane d4=lane&15 holds the
// query float4; candidate dot = per-lane partial + 4 shfl_xor. Exact top-8
// via packed u64 keys (monotone(score)<<32 | ~idx): order = (score desc,
// idx asc), branchless ins8u64, bit-exact score recovery. V-gather: lane i
// owns output element i. Overflow -> exact full-memory loop.
// ---------------------------------------------------------------------------
__global__ __launch_bounds__(64, 8)
void rescore_merge_kernel(const float* __restrict__ query,
                          const float* __restrict__ kmem,
                          const float* __restrict__ knr,
                          const unsigned* __restrict__ pcand,
                          const unsigned* __restrict__ pcnt,
                          const float* __restrict__ vmem,
                          const float* __restrict__ outputs,
                          const float* __restrict__ gate,
                          float* __restrict__ out) {
    __shared__ unsigned cands[NGRP * CMAX];
    const int gid = blockIdx.x;            // query id
    const int h = gid >> 10;
    const int n = gid & 1023;
    const int b = n >> 9;
    const int s = n & 511;
    const int lane = threadIdx.x;
    const int d4 = lane & 15;
    const int d5 = lane & 31;

    const float* qbase = query + ((((size_t)b * NHEADS + h) * SEQ + s) << 6);
    const float4 q4 = ((const float4*)qbase)[d4];
    float ssp = SS(q4);
    ssp += __shfl_xor(ssp, 1);
    ssp += __shfl_xor(ssp, 2);
    ssp += __shfl_xor(ssp, 4);
    ssp += __shfl_xor(ssp, 8);     // full ||q||^2 within each 16-lane group
    const float qs = 1.0f / (fmaxf(sqrtf(ssp), EPS) * 8.0f);

    // compact the 32 candidate lists into LDS (32-lane shfl prefix scan)
    const unsigned cg = pcnt[((size_t)gid << 5) + d5];
    const bool anyovf = (__ballot(cg > CMAX) != 0ULL);
    unsigned inc = cg;
#pragma unroll
    for (int d = 1; d < 32; d <<= 1) {
        unsigned t = __shfl_up(inc, d, 32);
        if (d5 >= d) inc += t;
    }
    const unsigned ct = __shfl(inc, 31, 32);
    const unsigned excl = inc - cg;
    if (lane < 32) {
        const unsigned* lp = pcand + (((size_t)gid << 5) + lane) * CMAX;
        const unsigned cc = cg > CMAX ? CMAX : cg;
        for (unsigned c = 0; c < cc; ++c) cands[excl + c] = lp[c];
    }
    __syncthreads();

    const float* kb = kmem + ((size_t)h << 20);
    const float* nb = knr + h * MMEM;

    unsigned long long top[8];
#pragma unroll
    for (int j = 0; j < 8; ++j) top[j] = 0ULL;

#define SCORE_KEY(IDX) ({                                                     \
        float4 kv = ((const float4*)(kb + ((size_t)(IDX) << 6)))[d4];         \
        float d = q4.x*kv.x + q4.y*kv.y + q4.z*kv.z + q4.w*kv.w;              \
        d += __shfl_xor(d, 1);                                                \
        d += __shfl_xor(d, 2);                                                \
        d += __shfl_xor(d, 4);                                                \
        d += __shfl_xor(d, 8);                                                \
        const float sc = d * qs * nb[IDX];                                    \
        unsigned su = __builtin_bit_cast(unsigned, sc);                       \
        unsigned ms = su ^ ((su >> 31) ? 0xFFFFFFFFu : 0x80000000u);          \
        ((unsigned long long)ms << 32) | (0xFFFFFFFFu - (unsigned)(IDX));     \
    })

    if (!anyovf) {
#pragma unroll 1
        for (unsigned c = 0; c < ct; ++c) {
            const unsigned idx = cands[c];
            ins8u64(top, SCORE_KEY(idx));
        }
    } else {
        // exact fallback: all memories (practically never taken)
#pragma unroll 1
        for (int m = 0; m < MMEM; ++m) ins8u64(top, SCORE_KEY(m));
    }
#undef SCORE_KEY

    // V-gather + gate blend: lane owns output element `lane`
    float acc = 0.0f;
    const float* vb = vmem + ((size_t)h << 20);
#pragma unroll
    for (int j = 0; j < 8; ++j) {
        const unsigned long long key = top[j];
        const unsigned idx = 0xFFFFFFFFu - (unsigned)(key & 0xFFFFFFFFu);
        const unsigned ms = (unsigned)(key >> 32);
        const unsigned su = ms ^ ((ms >> 31) ? 0x80000000u : 0xFFFFFFFFu);
        const float sc = __builtin_bit_cast(float, su);
        acc = fmaf(sc, vb[((size_t)idx << 6) + lane], acc);
    }

    const float gg = 1.0f / (1.0f + expf(-gate[h]));
    const size_t off = ((((size_t)b * NHEADS + h) * SEQ + s) << 6) + lane;
    out[off] = gg * acc + (1.0f - gg) * outputs[off];
}

// ---------------------------------------------------------------------------
// Fallback path (ws too small): fp32 scan + merge (previous rounds').
// ---------------------------------------------------------------------------
__global__ void knorm_kernel(const float* __restrict__ kmem,
                             float* __restrict__ knr) {
    int gid = blockIdx.x * 256 + threadIdx.x;
    int mem = gid >> 4;
    int d4  = gid & 15;
    float4 kv = reinterpret_cast<const float4*>(kmem)[(size_t)mem * 16 + d4];
    float ss = SS(kv);
    ss += __shfl_xor(ss, 1);
    ss += __shfl_xor(ss, 2);
    ss += __shfl_xor(ss, 4);
    ss += __shfl_xor(ss, 8);
    if (d4 == 0) knr[mem] = 1.0f / fmaxf(sqrtf(ss), EPS);
}

__global__ __launch_bounds__(64, 4)
void scan_kernel(const float* __restrict__ query,
                 const float* __restrict__ kmem,
                 const float* __restrict__ knr,
                 float* __restrict__ pscore,
                 int* __restrict__ pidx,
                 int P, int CH) {
    const int lane = threadIdx.x & 63;
    int bid = blockIdx.x;
    const int p  = bid % P;  bid /= P;
    const int qb = bid & 15; bid >>= 4;
    const int h  = bid;
    const int n  = qb * 64 + lane;
    const int b  = n >> 9;
    const int s  = n & 511;

    const float4* qp = reinterpret_cast<const float4*>(
        query + (((size_t)b * NHEADS + h) * SEQ + s) * HD);
    float q[HD];
    float ss = 0.0f;
#pragma unroll
    for (int i = 0; i < 16; ++i) {
        float4 v = qp[i];
        q[4*i+0] = v.x; q[4*i+1] = v.y; q[4*i+2] = v.z; q[4*i+3] = v.w;
        ss += SS(v);
    }
    const float rq = 1.0f / (fmaxf(sqrtf(ss), EPS) * 8.0f);
#pragma unroll
    for (int i = 0; i < HD; ++i) q[i] *= rq;

    float tv[8]; int ti[8];
#pragma unroll
    for (int j = 0; j < 8; ++j) { tv[j] = -INFINITY; ti[j] = 0; }

    const int m0 = p * CH;
    const float4* kp = reinterpret_cast<const float4*>(
        kmem + ((size_t)h * MMEM + m0) * HD);
    const float* knrp = knr + h * MMEM + m0;

    for (int mm = 0; mm < CH; ++mm) {
        float d0 = 0.f, d1 = 0.f, d2 = 0.f, d3 = 0.f;
#pragma unroll
        for (int i = 0; i < 16; ++i) {
            float4 kv = kp[(size_t)mm * 16 + i];
            d0 = fmaf(q[4*i+0], kv.x, d0);
            d1 = fmaf(q[4*i+1], kv.y, d1);
            d2 = fmaf(q[4*i+2], kv.z, d2);
            d3 = fmaf(q[4*i+3], kv.w, d3);
        }
        const float sim = ((d0 + d1) + (d2 + d3)) * knrp[mm];
        if (sim > tv[7]) {
            tv[7] = sim; ti[7] = m0 + mm;
#pragma unroll
            for (int j = 7; j > 0; --j) {
                if (tv[j] > tv[j-1]) {
                    float tf = tv[j]; tv[j] = tv[j-1]; tv[j-1] = tf;
                    int   tu = ti[j]; ti[j] = ti[j-1]; ti[j-1] = tu;
                }
            }
        }
    }

    const size_t base = (((size_t)h * NQ + n) * P + p) * 8;
#pragma unroll
    for (int j = 0; j < 8; ++j) { pscore[base+j] = tv[j]; pidx[base+j] = ti[j]; }
}

__global__ void merge_kernel(const float* __restrict__ pscore,
                             const int* __restrict__ pidx,
                             const float* __restrict__ vmem,
                             const float* __restrict__ outputs,
                             const float* __restrict__ gate,
                             float* __restrict__ out, int P) {
    const int t = blockIdx.x * 256 + threadIdx.x;
    const int h = t >> 10;
    const int n = t & 1023;
    const int b = n >> 9;
    const int s = n & 511;

    float tv[8]; int ti[8];
    const size_t base = ((size_t)h * NQ + n) * P * 8;
#pragma unroll
    for (int j = 0; j < 8; ++j) { tv[j] = pscore[base + j]; ti[j] = pidx[base + j]; }
    const int total = P * 8;
    for (int c = 8; c < total; ++c) {
        const float v = pscore[base + c];
        if (v > tv[7]) {
            tv[7] = v; ti[7] = pidx[base + c];
#pragma unroll
            for (int j = 7; j > 0; --j) {
                if (tv[j] > tv[j-1]) {
                    float tf = tv[j]; tv[j] = tv[j-1]; tv[j-1] = tf;
                    int   tu = ti[j]; ti[j] = ti[j-1]; ti[j-1] = tu;
                }
            }
        }
    }

    float4 acc[16];
#pragma unroll
    for (int i = 0; i < 16; ++i) acc[i] = make_float4(0.f, 0.f, 0.f, 0.f);
#pragma unroll
    for (int j = 0; j < 8; ++j) {
        const float4* vp = reinterpret_cast<const float4*>(
            vmem + ((size_t)h * MMEM + ti[j]) * HD);
        const float sc = tv[j];
#pragma unroll
        for (int i = 0; i < 16; ++i) {
            float4 v = vp[i];
            acc[i].x = fmaf(sc, v.x, acc[i].x);
            acc[i].y = fmaf(sc, v.y, acc[i].y);
            acc[i].z = fmaf(sc, v.z, acc[i].z);
            acc[i].w = fmaf(sc, v.w, acc[i].w);
        }
    }

    const float g  = 1.0f / (1.0f + expf(-gate[h]));
    const float og = 1.0f - g;
    const size_t off = (((size_t)b * NHEADS + h) * SEQ + s) * HD;
    const float4* op = reinterpret_cast<const float4*>(outputs + off);
    float4* dst = reinterpret_cast<float4*>(out + off);
#pragma unroll
    for (int i = 0; i < 16; ++i) {
        float4 o = op[i];
        float4 r;
        r.x = g * acc[i].x + og * o.x;
        r.y = g * acc[i].y + og * o.y;
        r.z = g * acc[i].z + og * o.z;
        r.w = g * acc[i].w + og * o.w;
        dst[i] = r;
    }
}

// ---------------------------------------------------------------------------
extern "C" void kernel_launch(void* const* d_in, const int* in_sizes, int n_in,
                              void* d_out, int out_size, void* d_ws, size_t ws_size,
                              hipStream_t stream) {
    const float* query   = (const float*)d_in[1];
    const float* outputs = (const float*)d_in[4];
    const float* gate    = (const float*)d_in[5];
    const float* kmem    = (const float*)d_in[6];
    const float* vmem    = (const float*)d_in[7];
    float* out = (float*)d_out;

    const size_t NQTOT    = (size_t)NHEADS * NQ;                 // 16384 queries
    const size_t sz_knr   = (size_t)NHEADS * MMEM * 4;           //  1.0 MB
    const size_t sz_kbf   = (size_t)NHEADS * MMEM * HD * 2;      // 33.5 MB
    const size_t sz_pmax  = NQTOT * NGRP * 4;                    //  2.1 MB
    const size_t sz_tauv  = NQTOT * 4;                           //  0.07 MB
    const size_t sz_pcand = NQTOT * NGRP * CMAX * 4;             // 16.8 MB
    const size_t sz_pcnt  = NQTOT * NGRP * 4;                    //  2.1 MB
    const size_t need = sz_knr + sz_kbf + sz_pmax + sz_tauv + sz_pcand + sz_pcnt;

    if (ws_size >= need) {
        char* w = (char*)d_ws;
        float*          knr   = (float*)w;          w += sz_knr;
        unsigned short* kbf   = (unsigned short*)w; w += sz_kbf;
        float*          pmax  = (float*)w;          w += sz_pmax;
        float*          tauv  = (float*)w;          w += sz_tauv;
        unsigned*       pcand = (unsigned*)w;       w += sz_pcand;
        unsigned*       pcnt  = (unsigned*)w;

        kprep_kernel<<<(NHEADS * 512 * 4 * 64) / 256, 256, 0, stream>>>(kmem, knr, kbf);
        scanA_kernel<<<NHEADS * 4 * NPART, 256, 0, stream>>>(query, kbf, pmax);
        taured_kernel<<<(int)(NQTOT / 256), 256, 0, stream>>>(pmax, tauv);
        scanB_kernel<<<NHEADS * 4 * NPART, 256, 0, stream>>>(query, kbf, tauv, pcand, pcnt);
        rescore_merge_kernel<<<(int)NQTOT, 64, 0, stream>>>(
            query, kmem, knr, pcand, pcnt, vmem, outputs, gate, out);
    } else {
        int P = 16;
        while (P > 4 &&
               (size_t)NHEADS * MMEM * 4 + (size_t)NHEADS * NQ * (size_t)P * 64 > ws_size)
            P >>= 1;
        const int CH = MMEM / P;

        float* knr    = (float*)d_ws;
        float* pscore = knr + (size_t)NHEADS * MMEM;
        int*   pidx   = (int*)(pscore + (size_t)NHEADS * NQ * (size_t)P * 8);

        knorm_kernel<<<(NHEADS * MMEM * 16) / 256, 256, 0, stream>>>(kmem, knr);
        scan_kernel<<<NHEADS * 16 * P, 64, 0, stream>>>(
            query, kmem, knr, pscore, pidx, P, CH);
        merge_kernel<<<(NHEADS * NQ) / 256, 256, 0, stream>>>(
            pscore, pidx, vmem, outputs, gate, out, P);
    }
}